// Round 1
// baseline (427.856 us; speedup 1.0000x reference)
//
#include <hip/hip_runtime.h>
#include <stdint.h>

#define SEQ    2048
#define DMODEL 1024
#define NH     16
#define HD     64
#define BATCH  4
#define MTOT   (BATCH*SEQ)   // 8192

typedef __attribute__((ext_vector_type(8))) short bf16x8;   // 8 bf16 = 4 VGPR
typedef __attribute__((ext_vector_type(4))) float f32x4;    // MFMA C/D frag

// ---------- helpers ----------
__device__ __forceinline__ unsigned short f2bf(float f) {
  union { float f; uint32_t u; } x; x.f = f;
  uint32_t u = x.u;
  u += 0x7FFFu + ((u >> 16) & 1u);          // RNE
  return (unsigned short)(u >> 16);
}

__device__ __forceinline__ void gload_lds16(const ushort* g, ushort* l) {
  // async global->LDS, 16B per lane; LDS dest = wave-uniform base + lane*16
  __builtin_amdgcn_global_load_lds(
      (const __attribute__((address_space(1))) uint32_t*)g,
      (__attribute__((address_space(3))) uint32_t*)l, 16, 0, 0);
}

// ---------- fp32 -> bf16 convert ----------
__global__ __launch_bounds__(256) void cvt_kernel(const float* __restrict__ in,
                                                  ushort* __restrict__ out, int n4) {
  int i = blockIdx.x * 256 + threadIdx.x;
  if (i >= n4) return;
  float4 v = ((const float4*)in)[i];
  ushort4 o;
  o.x = f2bf(v.x); o.y = f2bf(v.y); o.z = f2bf(v.z); o.w = f2bf(v.w);
  ((ushort4*)out)[i] = o;
}

// ---------- NT GEMM: C[M][N] = A[M][K] * B[N][K]^T + bias ----------
// MODE 0: QKV epilogue -> scatter bf16 q/k/v [B,H,S,HD], q pre-scaled by 1/8
// MODE 1: fp32 out + bias
template<int MODE>
__global__ __launch_bounds__(256)
void gemm_nt(const ushort* __restrict__ A, const ushort* __restrict__ B,
             const float* __restrict__ bias, float* __restrict__ outf,
             ushort* __restrict__ qo, ushort* __restrict__ ko, ushort* __restrict__ vo,
             int M, int N, int K)
{
  __shared__ ushort lda[128 * 64];
  __shared__ ushort ldb[128 * 64];
  const int tid = threadIdx.x;
  const int w = tid >> 6, lane = tid & 63;
  const int l15 = lane & 15, lg = lane >> 4;
  const int row0 = blockIdx.y * 128;
  const int col0 = blockIdx.x * 128;
  const int wm = (w >> 1) * 64, wn = (w & 1) * 64;   // wave 2x2 -> 64x64 out
  const int sr = lane >> 3, sc = (lane & 7) * 8;      // staging row/col within 8-row chunk

  f32x4 acc[4][4];
#pragma unroll
  for (int i = 0; i < 4; ++i)
#pragma unroll
    for (int j = 0; j < 4; ++j) acc[i][j] = (f32x4){0.f, 0.f, 0.f, 0.f};

  const ushort* Ablk = A + (size_t)row0 * K;
  const ushort* Bblk = B + (size_t)col0 * K;

  for (int kt = 0; kt < K; kt += 64) {
#pragma unroll
    for (int i = 0; i < 4; ++i) {
      const int is = w * 4 + i;   // wave-issue id 0..15 -> 8 rows each
      gload_lds16(Ablk + (size_t)(is * 8 + sr) * K + kt + sc, lda + is * 512);
      gload_lds16(Bblk + (size_t)(is * 8 + sr) * K + kt + sc, ldb + is * 512);
    }
    __syncthreads();
#pragma unroll
    for (int kk = 0; kk < 64; kk += 32) {
      bf16x8 af[4], bfr[4];
#pragma unroll
      for (int i = 0; i < 4; ++i)
        af[i] = *(const bf16x8*)&lda[(wm + i * 16 + l15) * 64 + kk + lg * 8];
#pragma unroll
      for (int j = 0; j < 4; ++j)
        bfr[j] = *(const bf16x8*)&ldb[(wn + j * 16 + l15) * 64 + kk + lg * 8];
#pragma unroll
      for (int i = 0; i < 4; ++i)
#pragma unroll
        for (int j = 0; j < 4; ++j)
          acc[i][j] = __builtin_amdgcn_mfma_f32_16x16x32_bf16(af[i], bfr[j], acc[i][j], 0, 0, 0);
    }
    __syncthreads();
  }

#pragma unroll
  for (int i = 0; i < 4; ++i)
#pragma unroll
    for (int j = 0; j < 4; ++j)
#pragma unroll
      for (int r = 0; r < 4; ++r) {
        const int m = row0 + wm + i * 16 + lg * 4 + r;
        const int n = col0 + wn + j * 16 + l15;
        const float val = acc[i][j][r] + bias[n];
        if (MODE == 1) {
          outf[(size_t)m * N + n] = val;
        } else {
          const int which = n >> 10;
          const int d = n & 1023;
          const int hh = d >> 6, hd = d & 63;
          const int bb = m >> 11, ss = m & 2047;
          const size_t idx = (((size_t)bb * NH + hh) * SEQ + ss) * HD + hd;
          if (which == 0)      qo[idx] = f2bf(val * 0.125f);  // fold 1/sqrt(64)
          else if (which == 1) ko[idx] = f2bf(val);
          else                 vo[idx] = f2bf(val);
        }
      }
}

// ---------- flash attention ----------
// grid: (S/128 q-tiles, B*H). block 256 = 4 waves, each wave owns 32 q-rows.
__global__ __launch_bounds__(256)
void attn_kernel(const ushort* __restrict__ Q, const ushort* __restrict__ Kg,
                 const ushort* __restrict__ Vg, ushort* __restrict__ O)
{
  __shared__ ushort ldk[64 * 64];        // K-tile [krow][hd], linear (gload_lds)
  __shared__ ushort ldvt[64 * 72];       // V-tile transposed [hd][krow], +8 pad
  __shared__ ushort ldp[4 * 32 * 72];    // per-wave P [32][72] bf16

  const int tid = threadIdx.x;
  const int w = tid >> 6, lane = tid & 63;
  const int l15 = lane & 15, lg = lane >> 4;
  const int qt = blockIdx.x, bh = blockIdx.y;
  const int b = bh >> 4, h = bh & 15;

  const ushort* Qb = Q + (size_t)bh * SEQ * HD;
  const ushort* Kb = Kg + (size_t)bh * SEQ * HD;
  const ushort* Vb = Vg + (size_t)bh * SEQ * HD;
  ushort* ldp_w = ldp + w * (32 * 72);

  // hoist Q fragments (A-operand layout) into registers
  const int qr0 = qt * 128 + w * 32;
  bf16x8 qf[2][2];
#pragma unroll
  for (int mi = 0; mi < 2; ++mi)
#pragma unroll
    for (int kf = 0; kf < 2; ++kf)
      qf[mi][kf] = *(const bf16x8*)&Qb[(size_t)(qr0 + mi * 16 + l15) * HD + kf * 32 + lg * 8];

  f32x4 acc_o[2][4];
  float m_run[2][4], l_run[2][4];
#pragma unroll
  for (int mi = 0; mi < 2; ++mi) {
#pragma unroll
    for (int nf = 0; nf < 4; ++nf) acc_o[mi][nf] = (f32x4){0.f, 0.f, 0.f, 0.f};
#pragma unroll
    for (int r = 0; r < 4; ++r) { m_run[mi][r] = -__builtin_inff(); l_run[mi][r] = 0.f; }
  }

  for (int kt = 0; kt < SEQ / 64; ++kt) {
    // --- stage K tile (async direct-to-LDS) ---
    const ushort* Ksrc = Kb + (size_t)kt * 64 * HD;
#pragma unroll
    for (int i = 0; i < 2; ++i) {
      const int is = w * 2 + i;
      gload_lds16(Ksrc + (size_t)(is * 8 + (lane >> 3)) * HD + (lane & 7) * 8, ldk + is * 512);
    }
    // --- stage V tile transposed ---
    const ushort* Vsrc = Vb + (size_t)kt * 64 * HD;
#pragma unroll
    for (int it = 0; it < 2; ++it) {
      const int idx = tid + it * 256;         // 0..511, 8 elems each
      const int r = idx >> 3, c8 = (idx & 7) * 8;
      uint4 dv = *(const uint4*)&Vsrc[r * 64 + c8];
      const ushort* ds = (const ushort*)&dv;
#pragma unroll
      for (int j = 0; j < 8; ++j) ldvt[(c8 + j) * 72 + r] = ds[j];
    }
    __syncthreads();

    // --- S = Q K^T (32x64 per wave) ---
    f32x4 accs[2][4];
#pragma unroll
    for (int mi = 0; mi < 2; ++mi)
#pragma unroll
      for (int nf = 0; nf < 4; ++nf) accs[mi][nf] = (f32x4){0.f, 0.f, 0.f, 0.f};
#pragma unroll
    for (int kf = 0; kf < 2; ++kf) {
      bf16x8 kfr[4];
#pragma unroll
      for (int nf = 0; nf < 4; ++nf)
        kfr[nf] = *(const bf16x8*)&ldk[(nf * 16 + l15) * 64 + kf * 32 + lg * 8];
#pragma unroll
      for (int mi = 0; mi < 2; ++mi)
#pragma unroll
        for (int nf = 0; nf < 4; ++nf)
          accs[mi][nf] = __builtin_amdgcn_mfma_f32_16x16x32_bf16(qf[mi][kf], kfr[nf], accs[mi][nf], 0, 0, 0);
    }

    // --- online softmax (rows live in C-layout: row = mi*16+lg*4+r) ---
#pragma unroll
    for (int mi = 0; mi < 2; ++mi)
#pragma unroll
      for (int r = 0; r < 4; ++r) {
        float mx = fmaxf(fmaxf(accs[mi][0][r], accs[mi][1][r]),
                         fmaxf(accs[mi][2][r], accs[mi][3][r]));
#pragma unroll
        for (int off = 1; off < 16; off <<= 1) mx = fmaxf(mx, __shfl_xor(mx, off));
        const float mold = m_run[mi][r];
        const float mnew = fmaxf(mold, mx);
        const float corr = __expf(mold - mnew);
        m_run[mi][r] = mnew;
        float psum = 0.f;
        const int prow = (mi * 16 + lg * 4 + r) * 72;
#pragma unroll
        for (int nf = 0; nf < 4; ++nf) {
          const float p = __expf(accs[mi][nf][r] - mnew);
          psum += p;
          ldp_w[prow + nf * 16 + l15] = f2bf(p);
          acc_o[mi][nf][r] *= corr;
        }
#pragma unroll
        for (int off = 1; off < 16; off <<= 1) psum += __shfl_xor(psum, off);
        l_run[mi][r] = l_run[mi][r] * corr + psum;
      }

    // --- O += P V (P from own-wave LDS, V^T from shared LDS) ---
#pragma unroll
    for (int kf = 0; kf < 2; ++kf) {
      bf16x8 pa[2], bv[4];
#pragma unroll
      for (int mi = 0; mi < 2; ++mi)
        pa[mi] = *(const bf16x8*)&ldp_w[(mi * 16 + l15) * 72 + kf * 32 + lg * 8];
#pragma unroll
      for (int nf = 0; nf < 4; ++nf)
        bv[nf] = *(const bf16x8*)&ldvt[(nf * 16 + l15) * 72 + kf * 32 + lg * 8];
#pragma unroll
      for (int mi = 0; mi < 2; ++mi)
#pragma unroll
        for (int nf = 0; nf < 4; ++nf)
          acc_o[mi][nf] = __builtin_amdgcn_mfma_f32_16x16x32_bf16(pa[mi], bv[nf], acc_o[mi][nf], 0, 0, 0);
    }
    __syncthreads();
  }

  // --- epilogue: normalize, write attn-out bf16 [B,S,H*HD] ---
#pragma unroll
  for (int mi = 0; mi < 2; ++mi)
#pragma unroll
    for (int nf = 0; nf < 4; ++nf)
#pragma unroll
      for (int r = 0; r < 4; ++r) {
        const int srow = qt * 128 + w * 32 + mi * 16 + lg * 4 + r;
        const int col = h * HD + nf * 16 + l15;
        O[(size_t)(b * SEQ + srow) * DMODEL + col] = f2bf(acc_o[mi][nf][r] / l_run[mi][r]);
      }
}

// ---------- launch ----------
extern "C" void kernel_launch(void* const* d_in, const int* in_sizes, int n_in,
                              void* d_out, int out_size, void* d_ws, size_t ws_size,
                              hipStream_t stream) {
  const float* x     = (const float*)d_in[0];
  const float* Wqkv  = (const float*)d_in[1];
  const float* bqkv  = (const float*)d_in[2];
  const float* Wproj = (const float*)d_in[3];
  const float* bproj = (const float*)d_in[4];
  float* out = (float*)d_out;

  char* ws = (char*)d_ws;
  ushort* x_bf     = (ushort*)ws;                      // 16MB (reused as attn-out)
  ushort* ao       = x_bf;
  ushort* wqkv_bf  = (ushort*)(ws + (16u << 20));      // 6MB
  ushort* wproj_bf = (ushort*)(ws + (22u << 20));      // 2MB
  ushort* q        = (ushort*)(ws + (24u << 20));      // 16MB each
  ushort* k        = (ushort*)(ws + (40u << 20));
  ushort* v        = (ushort*)(ws + (56u << 20));

  cvt_kernel<<<(MTOT * DMODEL / 4) / 256, 256, 0, stream>>>(x, x_bf, MTOT * DMODEL / 4);
  cvt_kernel<<<(3 * DMODEL * DMODEL / 4) / 256, 256, 0, stream>>>(Wqkv, wqkv_bf, 3 * DMODEL * DMODEL / 4);
  cvt_kernel<<<(DMODEL * DMODEL / 4) / 256, 256, 0, stream>>>(Wproj, wproj_bf, DMODEL * DMODEL / 4);

  gemm_nt<0><<<dim3(3 * DMODEL / 128, MTOT / 128), 256, 0, stream>>>(
      x_bf, wqkv_bf, bqkv, nullptr, q, k, v, MTOT, 3 * DMODEL, DMODEL);

  attn_kernel<<<dim3(SEQ / 128, BATCH * NH), 256, 0, stream>>>(q, k, v, ao);

  gemm_nt<1><<<dim3(DMODEL / 128, MTOT / 128), 256, 0, stream>>>(
      ao, wproj_bf, bproj, out, nullptr, nullptr, nullptr, MTOT, DMODEL, DMODEL);
}

// Round 2
// 374.855 us; speedup vs baseline: 1.1414x; 1.1414x over previous
//
#include <hip/hip_runtime.h>
#include <stdint.h>

#define SEQ    2048
#define DMODEL 1024
#define NH     16
#define HD     64
#define BATCH  4
#define MTOT   (BATCH*SEQ)   // 8192

typedef __attribute__((ext_vector_type(8))) short bf16x8;   // 8 bf16 = 4 VGPR
typedef __attribute__((ext_vector_type(4))) float f32x4;    // MFMA C/D frag

#define QSCALE (0.125f * 1.44269504088896f)   // 1/sqrt(64) * log2(e)

// ---------- helpers ----------
__device__ __forceinline__ unsigned short f2bf(float f) {
  union { float f; uint32_t u; } x; x.f = f;
  uint32_t u = x.u;
  u += 0x7FFFu + ((u >> 16) & 1u);          // RNE
  return (unsigned short)(u >> 16);
}

__device__ __forceinline__ float exp2_fast(float x) {
#if __has_builtin(__builtin_amdgcn_exp2f)
  return __builtin_amdgcn_exp2f(x);
#else
  return __expf(x * 0.69314718056f);
#endif
}

__device__ __forceinline__ void gload_lds16(const ushort* g, ushort* l) {
  // async global->LDS, 16B per lane; LDS dest = wave-uniform base + lane*16
  __builtin_amdgcn_global_load_lds(
      (const __attribute__((address_space(1))) uint32_t*)g,
      (__attribute__((address_space(3))) uint32_t*)l, 16, 0, 0);
}

// ---------- fp32 -> bf16 convert ----------
__global__ __launch_bounds__(256) void cvt_kernel(const float* __restrict__ in,
                                                  ushort* __restrict__ out, int n4) {
  int i = blockIdx.x * 256 + threadIdx.x;
  if (i >= n4) return;
  float4 v = ((const float4*)in)[i];
  ushort4 o;
  o.x = f2bf(v.x); o.y = f2bf(v.y); o.z = f2bf(v.z); o.w = f2bf(v.w);
  ((ushort4*)out)[i] = o;
}

// ---------- NT GEMM: C[M][N] = A[M][K] * B[N][K]^T + bias ----------
// MODE 0: QKV epilogue -> q,k bf16 [B,H,S,HD] (q pre-scaled by QSCALE),
//         v written TRANSPOSED bf16 [B,H,HD,SEQ] (packed ushort4 stores)
// MODE 1: fp32 out + bias
template<int MODE>
__global__ __launch_bounds__(256)
void gemm_nt(const ushort* __restrict__ A, const ushort* __restrict__ B,
             const float* __restrict__ bias, float* __restrict__ outf,
             ushort* __restrict__ qo, ushort* __restrict__ ko, ushort* __restrict__ vto,
             int M, int N, int K)
{
  __shared__ ushort lda[128 * 64];
  __shared__ ushort ldb[128 * 64];
  const int tid = threadIdx.x;
  const int w = tid >> 6, lane = tid & 63;
  const int l15 = lane & 15, lg = lane >> 4;
  const int row0 = blockIdx.y * 128;
  const int col0 = blockIdx.x * 128;
  const int wm = (w >> 1) * 64, wn = (w & 1) * 64;   // wave 2x2 -> 64x64 out
  const int sr = lane >> 3, sc = (lane & 7) * 8;      // staging row/col within 8-row chunk

  f32x4 acc[4][4];
#pragma unroll
  for (int i = 0; i < 4; ++i)
#pragma unroll
    for (int j = 0; j < 4; ++j) acc[i][j] = (f32x4){0.f, 0.f, 0.f, 0.f};

  const ushort* Ablk = A + (size_t)row0 * K;
  const ushort* Bblk = B + (size_t)col0 * K;

  for (int kt = 0; kt < K; kt += 64) {
#pragma unroll
    for (int i = 0; i < 4; ++i) {
      const int is = w * 4 + i;   // wave-issue id 0..15 -> 8 rows each
      gload_lds16(Ablk + (size_t)(is * 8 + sr) * K + kt + sc, lda + is * 512);
      gload_lds16(Bblk + (size_t)(is * 8 + sr) * K + kt + sc, ldb + is * 512);
    }
    __syncthreads();
#pragma unroll
    for (int kk = 0; kk < 64; kk += 32) {
      bf16x8 af[4], bfr[4];
#pragma unroll
      for (int i = 0; i < 4; ++i)
        af[i] = *(const bf16x8*)&lda[(wm + i * 16 + l15) * 64 + kk + lg * 8];
#pragma unroll
      for (int j = 0; j < 4; ++j)
        bfr[j] = *(const bf16x8*)&ldb[(wn + j * 16 + l15) * 64 + kk + lg * 8];
#pragma unroll
      for (int i = 0; i < 4; ++i)
#pragma unroll
        for (int j = 0; j < 4; ++j)
          acc[i][j] = __builtin_amdgcn_mfma_f32_16x16x32_bf16(af[i], bfr[j], acc[i][j], 0, 0, 0);
    }
    __syncthreads();
  }

#pragma unroll
  for (int i = 0; i < 4; ++i)
#pragma unroll
    for (int j = 0; j < 4; ++j) {
      const int n = col0 + wn + j * 16 + l15;
      const int m0 = row0 + wm + i * 16 + lg * 4;
      const float bn = bias[n];
      if (MODE == 1) {
#pragma unroll
        for (int r = 0; r < 4; ++r)
          outf[(size_t)(m0 + r) * N + n] = acc[i][j][r] + bn;
      } else {
        const int d = n & 1023;
        const int hh = d >> 6, hd = d & 63;
        const int bb = m0 >> 11, ss0 = m0 & 2047;
        const int which = n >> 10;
        if (which == 2) {
          // V^T: [B,H,HD,SEQ]; 4 consecutive seq positions per lane -> ushort4
          ushort4 pk;
          pk.x = f2bf(acc[i][j][0] + bn);
          pk.y = f2bf(acc[i][j][1] + bn);
          pk.z = f2bf(acc[i][j][2] + bn);
          pk.w = f2bf(acc[i][j][3] + bn);
          *(ushort4*)&vto[(((size_t)bb * NH + hh) * HD + hd) * SEQ + ss0] = pk;
        } else {
          const size_t idx = (((size_t)bb * NH + hh) * SEQ + ss0) * HD + hd;
#pragma unroll
          for (int r = 0; r < 4; ++r) {
            const float val = acc[i][j][r] + bn;
            if (which == 0) qo[idx + (size_t)r * HD] = f2bf(val * QSCALE);
            else            ko[idx + (size_t)r * HD] = f2bf(val);
          }
        }
      }
    }
}

// ---------- flash attention ----------
// grid: (S/128 q-tiles, B*H). block 256 = 4 waves, each wave owns 32 q-rows.
// K tile [64 key][64 hd] and V^T tile [64 hd][64 key] staged via global_load_lds
// with XOR-swizzled (cb ^= row&7) per-lane global source; reads apply same XOR.
__global__ __launch_bounds__(256)
void attn_kernel(const ushort* __restrict__ Q, const ushort* __restrict__ Kg,
                 const ushort* __restrict__ Vtg, ushort* __restrict__ O)
{
  __shared__ ushort ldk[64 * 64];        // swizzled K tile
  __shared__ ushort ldvt[64 * 64];       // swizzled V^T tile
  __shared__ ushort ldp[4 * 32 * 72];    // per-wave P [32][72] bf16

  const int tid = threadIdx.x;
  const int w = tid >> 6, lane = tid & 63;
  const int l15 = lane & 15, lg = lane >> 4;
  const int qt = blockIdx.x, bh = blockIdx.y;
  const int b = bh >> 4, h = bh & 15;

  const ushort* Qb = Q + (size_t)bh * SEQ * HD;
  const ushort* Kb = Kg + (size_t)bh * SEQ * HD;
  const ushort* Vtb = Vtg + (size_t)bh * HD * SEQ;
  ushort* ldp_w = ldp + w * (32 * 72);

  const int srow = lane >> 3;            // staging row within 8-row chunk
  const int scb = (lane & 7) ^ srow;     // swizzled source col-block (16B units)
  const int rswz = l15 & 7;              // read-side XOR key

  // hoist Q fragments (A-operand layout) into registers
  const int qr0 = qt * 128 + w * 32;
  bf16x8 qf[2][2];
#pragma unroll
  for (int mi = 0; mi < 2; ++mi)
#pragma unroll
    for (int kf = 0; kf < 2; ++kf)
      qf[mi][kf] = *(const bf16x8*)&Qb[(size_t)(qr0 + mi * 16 + l15) * HD + kf * 32 + lg * 8];

  f32x4 acc_o[2][4];
  float m_run[2][4], l_run[2][4];
#pragma unroll
  for (int mi = 0; mi < 2; ++mi) {
#pragma unroll
    for (int nf = 0; nf < 4; ++nf) acc_o[mi][nf] = (f32x4){0.f, 0.f, 0.f, 0.f};
#pragma unroll
    for (int r = 0; r < 4; ++r) { m_run[mi][r] = -__builtin_inff(); l_run[mi][r] = 0.f; }
  }

  for (int kt = 0; kt < SEQ / 64; ++kt) {
    // --- stage K tile (row = key, 64x64, row stride HD) ---
    const ushort* Ksrc = Kb + (size_t)kt * 64 * HD;
#pragma unroll
    for (int i = 0; i < 2; ++i) {
      const int is = w * 2 + i;
      gload_lds16(Ksrc + (size_t)(is * 8 + srow) * HD + scb * 8, ldk + is * 512);
    }
    // --- stage V^T tile (row = hd, 64x64, row stride SEQ) ---
    const ushort* Vsrc = Vtb + (size_t)kt * 64;
#pragma unroll
    for (int i = 0; i < 2; ++i) {
      const int is = w * 2 + i;
      gload_lds16(Vsrc + (size_t)(is * 8 + srow) * SEQ + scb * 8, ldvt + is * 512);
    }
    __syncthreads();

    // --- S = Q K^T (32x64 per wave), logits already in log2 domain ---
    f32x4 accs[2][4];
#pragma unroll
    for (int mi = 0; mi < 2; ++mi)
#pragma unroll
      for (int nf = 0; nf < 4; ++nf) accs[mi][nf] = (f32x4){0.f, 0.f, 0.f, 0.f};
#pragma unroll
    for (int kf = 0; kf < 2; ++kf) {
      bf16x8 kfr[4];
#pragma unroll
      for (int nf = 0; nf < 4; ++nf)
        kfr[nf] = *(const bf16x8*)&ldk[(nf * 16 + l15) * 64 + ((4 * kf + lg) ^ rswz) * 8];
#pragma unroll
      for (int mi = 0; mi < 2; ++mi)
#pragma unroll
        for (int nf = 0; nf < 4; ++nf)
          accs[mi][nf] = __builtin_amdgcn_mfma_f32_16x16x32_bf16(qf[mi][kf], kfr[nf], accs[mi][nf], 0, 0, 0);
    }

    // --- online softmax (rows live in C-layout: row = mi*16+lg*4+r) ---
#pragma unroll
    for (int mi = 0; mi < 2; ++mi)
#pragma unroll
      for (int r = 0; r < 4; ++r) {
        float mx = fmaxf(fmaxf(accs[mi][0][r], accs[mi][1][r]),
                         fmaxf(accs[mi][2][r], accs[mi][3][r]));
#pragma unroll
        for (int off = 1; off < 16; off <<= 1) mx = fmaxf(mx, __shfl_xor(mx, off));
        const float mold = m_run[mi][r];
        const float mnew = fmaxf(mold, mx);
        const float corr = exp2_fast(mold - mnew);
        m_run[mi][r] = mnew;
        float psum = 0.f;
        const int prow = (mi * 16 + lg * 4 + r) * 72;
#pragma unroll
        for (int nf = 0; nf < 4; ++nf) {
          const float p = exp2_fast(accs[mi][nf][r] - mnew);
          psum += p;
          ldp_w[prow + nf * 16 + l15] = f2bf(p);
          acc_o[mi][nf][r] *= corr;
        }
#pragma unroll
        for (int off = 1; off < 16; off <<= 1) psum += __shfl_xor(psum, off);
        l_run[mi][r] = l_run[mi][r] * corr + psum;
      }

    // --- O += P V (P from own-wave LDS, V^T from swizzled LDS) ---
#pragma unroll
    for (int kf = 0; kf < 2; ++kf) {
      bf16x8 pa[2], bv[4];
#pragma unroll
      for (int mi = 0; mi < 2; ++mi)
        pa[mi] = *(const bf16x8*)&ldp_w[(mi * 16 + l15) * 72 + kf * 32 + lg * 8];
#pragma unroll
      for (int nf = 0; nf < 4; ++nf)
        bv[nf] = *(const bf16x8*)&ldvt[(nf * 16 + l15) * 64 + ((4 * kf + lg) ^ rswz) * 8];
#pragma unroll
      for (int mi = 0; mi < 2; ++mi)
#pragma unroll
        for (int nf = 0; nf < 4; ++nf)
          acc_o[mi][nf] = __builtin_amdgcn_mfma_f32_16x16x32_bf16(pa[mi], bv[nf], acc_o[mi][nf], 0, 0, 0);
    }
    __syncthreads();
  }

  // --- epilogue: normalize, write attn-out bf16 [B,S,H*HD] ---
#pragma unroll
  for (int mi = 0; mi < 2; ++mi)
#pragma unroll
    for (int nf = 0; nf < 4; ++nf)
#pragma unroll
      for (int r = 0; r < 4; ++r) {
        const int srw = qt * 128 + w * 32 + mi * 16 + lg * 4 + r;
        const int col = h * HD + nf * 16 + l15;
        O[(size_t)(b * SEQ + srw) * DMODEL + col] = f2bf(acc_o[mi][nf][r] / l_run[mi][r]);
      }
}

// ---------- launch ----------
extern "C" void kernel_launch(void* const* d_in, const int* in_sizes, int n_in,
                              void* d_out, int out_size, void* d_ws, size_t ws_size,
                              hipStream_t stream) {
  const float* x     = (const float*)d_in[0];
  const float* Wqkv  = (const float*)d_in[1];
  const float* bqkv  = (const float*)d_in[2];
  const float* Wproj = (const float*)d_in[3];
  const float* bproj = (const float*)d_in[4];
  float* out = (float*)d_out;

  char* ws = (char*)d_ws;
  ushort* x_bf     = (ushort*)ws;                      // 16MB (reused as attn-out)
  ushort* ao       = x_bf;
  ushort* wqkv_bf  = (ushort*)(ws + (16u << 20));      // 6MB
  ushort* wproj_bf = (ushort*)(ws + (22u << 20));      // 2MB
  ushort* q        = (ushort*)(ws + (24u << 20));      // 16MB each
  ushort* k        = (ushort*)(ws + (40u << 20));
  ushort* vt       = (ushort*)(ws + (56u << 20));      // V transposed [B,H,HD,SEQ]

  cvt_kernel<<<(MTOT * DMODEL / 4) / 256, 256, 0, stream>>>(x, x_bf, MTOT * DMODEL / 4);
  cvt_kernel<<<(3 * DMODEL * DMODEL / 4) / 256, 256, 0, stream>>>(Wqkv, wqkv_bf, 3 * DMODEL * DMODEL / 4);
  cvt_kernel<<<(DMODEL * DMODEL / 4) / 256, 256, 0, stream>>>(Wproj, wproj_bf, DMODEL * DMODEL / 4);

  gemm_nt<0><<<dim3(3 * DMODEL / 128, MTOT / 128), 256, 0, stream>>>(
      x_bf, wqkv_bf, bqkv, nullptr, q, k, vt, MTOT, 3 * DMODEL, DMODEL);

  attn_kernel<<<dim3(SEQ / 128, BATCH * NH), 256, 0, stream>>>(q, k, vt, ao);

  gemm_nt<1><<<dim3(DMODEL / 128, MTOT / 128), 256, 0, stream>>>(
      ao, wproj_bf, bproj, out, nullptr, nullptr, nullptr, MTOT, DMODEL, DMODEL);
}

// Round 3
// 250.057 us; speedup vs baseline: 1.7110x; 1.4991x over previous
//
#include <hip/hip_runtime.h>
#include <stdint.h>

#define SEQ    2048
#define DMODEL 1024
#define NH     16
#define HD     64
#define BATCH  4
#define MTOT   (BATCH*SEQ)   // 8192
#define NT     (SEQ/64)      // 32 K-tiles

typedef __attribute__((ext_vector_type(8))) short bf16x8;   // 8 bf16 = 4 VGPR
typedef __attribute__((ext_vector_type(4))) float f32x4;    // MFMA C/D frag
typedef __attribute__((ext_vector_type(2))) unsigned int uint2v;

#define QSCALE (0.125f * 1.44269504088896f)   // 1/sqrt(64) * log2(e)

// ---------- helpers ----------
__device__ __forceinline__ unsigned short f2bf(float f) {
  union { float f; uint32_t u; } x; x.f = f;
  uint32_t u = x.u;
  u += 0x7FFFu + ((u >> 16) & 1u);          // RNE
  return (unsigned short)(u >> 16);
}

__device__ __forceinline__ float exp2_fast(float x) {
#if __has_builtin(__builtin_amdgcn_exp2f)
  return __builtin_amdgcn_exp2f(x);
#else
  return __expf(x * 0.69314718056f);
#endif
}

__device__ __forceinline__ uint32_t cvt_pk_bf16(float lo, float hi) {
  uint32_t r;
  asm("v_cvt_pk_bf16_f32 %0, %1, %2" : "=v"(r) : "v"(lo), "v"(hi));
  return r;
}

// x' = {x[0:32], y[0:32]}, y' = {x[32:64], y[32:64]}
__device__ __forceinline__ void swap32(uint32_t& x, uint32_t& y) {
#if __has_builtin(__builtin_amdgcn_permlane32_swap)
  uint2v r = __builtin_amdgcn_permlane32_swap(x, y, false, false);
  x = r[0]; y = r[1];
#else
  unsigned int xs = __shfl_xor((unsigned int)x, 32);
  unsigned int ys = __shfl_xor((unsigned int)y, 32);
  const bool lo = ((threadIdx.x & 63) & 32) == 0;
  x = lo ? x : (uint32_t)ys;
  y = lo ? (uint32_t)xs : y;
#endif
}

// per 32-half: x' = {x[0:16], y[0:16]}, y' = {x[16:32], y[16:32]}
__device__ __forceinline__ void swap16(uint32_t& x, uint32_t& y) {
#if __has_builtin(__builtin_amdgcn_permlane16_swap)
  uint2v r = __builtin_amdgcn_permlane16_swap(x, y, false, false);
  x = r[0]; y = r[1];
#else
  unsigned int xs = __shfl_xor((unsigned int)x, 16);
  unsigned int ys = __shfl_xor((unsigned int)y, 16);
  const bool lo = ((threadIdx.x & 63) & 16) == 0;
  x = lo ? x : (uint32_t)ys;
  y = lo ? (uint32_t)xs : y;
#endif
}

__device__ __forceinline__ void gload_lds16(const ushort* g, ushort* l) {
  __builtin_amdgcn_global_load_lds(
      (const __attribute__((address_space(1))) uint32_t*)g,
      (__attribute__((address_space(3))) uint32_t*)l, 16, 0, 0);
}

// ---------- fp32 -> bf16 convert ----------
__global__ __launch_bounds__(256) void cvt_kernel(const float* __restrict__ in,
                                                  ushort* __restrict__ out, int n4) {
  int i = blockIdx.x * 256 + threadIdx.x;
  if (i >= n4) return;
  float4 v = ((const float4*)in)[i];
  ushort4 o;
  o.x = f2bf(v.x); o.y = f2bf(v.y); o.z = f2bf(v.z); o.w = f2bf(v.w);
  ((ushort4*)out)[i] = o;
}

// ---------- NT GEMM: C[M][N] = A[M][K] * B[N][K]^T + bias ----------
template<int MODE>
__global__ __launch_bounds__(256)
void gemm_nt(const ushort* __restrict__ A, const ushort* __restrict__ B,
             const float* __restrict__ bias, float* __restrict__ outf,
             ushort* __restrict__ qo, ushort* __restrict__ ko, ushort* __restrict__ vto,
             int M, int N, int K)
{
  __shared__ ushort lda[128 * 64];
  __shared__ ushort ldb[128 * 64];
  const int tid = threadIdx.x;
  const int w = tid >> 6, lane = tid & 63;
  const int l15 = lane & 15, lg = lane >> 4;
  const int row0 = blockIdx.y * 128;
  const int col0 = blockIdx.x * 128;
  const int wm = (w >> 1) * 64, wn = (w & 1) * 64;
  const int sr = lane >> 3, sc = (lane & 7) * 8;

  f32x4 acc[4][4];
#pragma unroll
  for (int i = 0; i < 4; ++i)
#pragma unroll
    for (int j = 0; j < 4; ++j) acc[i][j] = (f32x4){0.f, 0.f, 0.f, 0.f};

  const ushort* Ablk = A + (size_t)row0 * K;
  const ushort* Bblk = B + (size_t)col0 * K;

  for (int kt = 0; kt < K; kt += 64) {
#pragma unroll
    for (int i = 0; i < 4; ++i) {
      const int is = w * 4 + i;
      gload_lds16(Ablk + (size_t)(is * 8 + sr) * K + kt + sc, lda + is * 512);
      gload_lds16(Bblk + (size_t)(is * 8 + sr) * K + kt + sc, ldb + is * 512);
    }
    __syncthreads();
#pragma unroll
    for (int kk = 0; kk < 64; kk += 32) {
      bf16x8 af[4], bfr[4];
#pragma unroll
      for (int i = 0; i < 4; ++i)
        af[i] = *(const bf16x8*)&lda[(wm + i * 16 + l15) * 64 + kk + lg * 8];
#pragma unroll
      for (int j = 0; j < 4; ++j)
        bfr[j] = *(const bf16x8*)&ldb[(wn + j * 16 + l15) * 64 + kk + lg * 8];
#pragma unroll
      for (int i = 0; i < 4; ++i)
#pragma unroll
        for (int j = 0; j < 4; ++j)
          acc[i][j] = __builtin_amdgcn_mfma_f32_16x16x32_bf16(af[i], bfr[j], acc[i][j], 0, 0, 0);
    }
    __syncthreads();
  }

#pragma unroll
  for (int i = 0; i < 4; ++i)
#pragma unroll
    for (int j = 0; j < 4; ++j) {
      const int n = col0 + wn + j * 16 + l15;
      const int m0 = row0 + wm + i * 16 + lg * 4;
      const float bn = bias[n];
      if (MODE == 1) {
#pragma unroll
        for (int r = 0; r < 4; ++r)
          outf[(size_t)(m0 + r) * N + n] = acc[i][j][r] + bn;
      } else {
        const int d = n & 1023;
        const int hh = d >> 6, hd = d & 63;
        const int bb = m0 >> 11, ss0 = m0 & 2047;
        const int which = n >> 10;
        if (which == 2) {
          ushort4 pk;
          pk.x = f2bf(acc[i][j][0] + bn);
          pk.y = f2bf(acc[i][j][1] + bn);
          pk.z = f2bf(acc[i][j][2] + bn);
          pk.w = f2bf(acc[i][j][3] + bn);
          *(ushort4*)&vto[(((size_t)bb * NH + hh) * HD + hd) * SEQ + ss0] = pk;
        } else {
          const size_t idx = (((size_t)bb * NH + hh) * SEQ + ss0) * HD + hd;
#pragma unroll
          for (int r = 0; r < 4; ++r) {
            const float val = acc[i][j][r] + bn;
            if (which == 0) qo[idx + (size_t)r * HD] = f2bf(val * QSCALE);
            else            ko[idx + (size_t)r * HD] = f2bf(val);
          }
        }
      }
    }
}

// ---------- flash attention, swapped-QK^T (S^T / O^T in registers) ----------
// grid: (S/128, B*H), 4 waves, each wave 32 q-rows.
// S^T = mfma(A=K, B=Q): key = lg*4+r (row), q = l15 (col) -> row-reduce is
// in-lane (16 vals) + 2 shuffles. P stays in registers: cvt_pk + permlane
// swap network re-fragments P^T as the PV B-operand. O^T = mfma(V^T, P^T).
__global__ __launch_bounds__(256)
void attn_kernel(const ushort* __restrict__ Q, const ushort* __restrict__ Kg,
                 const ushort* __restrict__ Vtg, ushort* __restrict__ O)
{
  __shared__ ushort ldk[2][64 * 64];     // swizzled K tiles (double buffer)
  __shared__ ushort ldvt[2][64 * 64];    // swizzled V^T tiles

  const int tid = threadIdx.x;
  const int w = tid >> 6, lane = tid & 63;
  const int l15 = lane & 15, lg = lane >> 4;
  const int qt = blockIdx.x, bh = blockIdx.y;
  const int b = bh >> 4, h = bh & 15;

  const ushort* Qb = Q + (size_t)bh * SEQ * HD;
  const ushort* Kb = Kg + (size_t)bh * SEQ * HD;
  const ushort* Vtb = Vtg + (size_t)bh * HD * SEQ;

  const int srow = lane >> 3;
  const int scb = (lane & 7) ^ srow;     // swizzled source col-block (16B units)
  const int rswz = l15 & 7;              // read-side XOR key

  // Q fragments (B-operand: col=q=l15, k=d=dk*32+lg*8)
  const int qr0 = qt * 128 + w * 32;
  bf16x8 qf[2][2];
#pragma unroll
  for (int mi = 0; mi < 2; ++mi)
#pragma unroll
    for (int dk = 0; dk < 2; ++dk)
      qf[mi][dk] = *(const bf16x8*)&Qb[(size_t)(qr0 + mi * 16 + l15) * HD + dk * 32 + lg * 8];

  f32x4 acc_o[2][4];                     // O^T: row hd = nf*16+lg*4+r, col q = l15
  float m_run[2], l_run[2];
#pragma unroll
  for (int mi = 0; mi < 2; ++mi) {
#pragma unroll
    for (int nf = 0; nf < 4; ++nf) acc_o[mi][nf] = (f32x4){0.f, 0.f, 0.f, 0.f};
    m_run[mi] = -1e30f; l_run[mi] = 0.f;
  }

#define STAGE(bufi, tile) do {                                                        \
    const ushort* Ks_ = Kb + (size_t)(tile) * 64 * HD;                                \
    const ushort* Vs_ = Vtb + (size_t)(tile) * 64;                                    \
    _Pragma("unroll")                                                                 \
    for (int i_ = 0; i_ < 2; ++i_) {                                                  \
      const int is_ = w * 2 + i_;                                                     \
      gload_lds16(Ks_ + (size_t)(is_ * 8 + srow) * HD + scb * 8, &ldk[bufi][is_ * 512]);   \
      gload_lds16(Vs_ + (size_t)(is_ * 8 + srow) * SEQ + scb * 8, &ldvt[bufi][is_ * 512]); \
    }                                                                                 \
  } while (0)

  int cur = 0;
  STAGE(0, 0);
  __syncthreads();

  for (int kt = 0; kt < NT; ++kt) {
    if (kt + 1 < NT) STAGE(cur ^ 1, kt + 1);   // prefetch overlaps compute below

    // --- S^T = K Q^T : accs[a][mi], key = a*16+lg*4+r, q = mi*16+l15 ---
    f32x4 accs[4][2];
#pragma unroll
    for (int a = 0; a < 4; ++a)
#pragma unroll
      for (int mi = 0; mi < 2; ++mi) accs[a][mi] = (f32x4){0.f, 0.f, 0.f, 0.f};
#pragma unroll
    for (int dk = 0; dk < 2; ++dk) {
      bf16x8 kfr[4];
#pragma unroll
      for (int a = 0; a < 4; ++a)
        kfr[a] = *(const bf16x8*)&ldk[cur][(a * 16 + l15) * 64 + ((dk * 4 + lg) ^ rswz) * 8];
#pragma unroll
      for (int a = 0; a < 4; ++a)
#pragma unroll
        for (int mi = 0; mi < 2; ++mi)
          accs[a][mi] = __builtin_amdgcn_mfma_f32_16x16x32_bf16(kfr[a], qf[mi][dk], accs[a][mi], 0, 0, 0);
    }

    // --- online softmax (log2 domain), in-lane + 2 shuffles per mi ---
#pragma unroll
    for (int mi = 0; mi < 2; ++mi) {
      float mx = accs[0][mi][0];
#pragma unroll
      for (int a = 0; a < 4; ++a)
#pragma unroll
        for (int r = 0; r < 4; ++r) mx = fmaxf(mx, accs[a][mi][r]);
      mx = fmaxf(mx, __shfl_xor(mx, 16));
      mx = fmaxf(mx, __shfl_xor(mx, 32));
      if (!__all(mx - m_run[mi] <= 8.0f)) {          // T13 defer-max
        const float mnew = fmaxf(m_run[mi], mx);
        const float corr = exp2_fast(m_run[mi] - mnew);
        l_run[mi] *= corr;
#pragma unroll
        for (int nf = 0; nf < 4; ++nf)
#pragma unroll
          for (int r = 0; r < 4; ++r) acc_o[mi][nf][r] *= corr;
        m_run[mi] = mnew;
      }
      const float m = m_run[mi];
      float ps = 0.f;
#pragma unroll
      for (int a = 0; a < 4; ++a)
#pragma unroll
        for (int r = 0; r < 4; ++r) {
          const float p = exp2_fast(accs[a][mi][r] - m);
          accs[a][mi][r] = p;
          ps += p;
        }
      ps += __shfl_xor(ps, 16);
      ps += __shfl_xor(ps, 32);
      l_run[mi] += ps;
    }

    // --- O^T += V^T P^T; P^T re-fragmented in-register ---
#pragma unroll
    for (int kk = 0; kk < 2; ++kk) {
      bf16x8 vv[4];
#pragma unroll
      for (int nf = 0; nf < 4; ++nf)
        vv[nf] = *(const bf16x8*)&ldvt[cur][(nf * 16 + l15) * 64 + ((kk * 4 + lg) ^ rswz) * 8];
#pragma unroll
      for (int mi = 0; mi < 2; ++mi) {
        // lane lg holds keys {lg*4+r} (kf even) and {16+lg*4+r} (kf odd) of this
        // 32-key block; network yields dwords = keys 8lg..8lg+7 (B-operand).
        uint32_t a0 = cvt_pk_bf16(accs[2 * kk][mi][0], accs[2 * kk][mi][1]);
        uint32_t a1 = cvt_pk_bf16(accs[2 * kk][mi][2], accs[2 * kk][mi][3]);
        uint32_t b0 = cvt_pk_bf16(accs[2 * kk + 1][mi][0], accs[2 * kk + 1][mi][1]);
        uint32_t b1 = cvt_pk_bf16(accs[2 * kk + 1][mi][2], accs[2 * kk + 1][mi][3]);
        swap32(a0, b0); swap32(a1, b1);
        swap16(a0, b0); swap16(a1, b1);
        union { uint32_t d[4]; bf16x8 v; } pu;
        pu.d[0] = a0; pu.d[1] = a1; pu.d[2] = b0; pu.d[3] = b1;
#pragma unroll
        for (int nf = 0; nf < 4; ++nf)
          acc_o[mi][nf] = __builtin_amdgcn_mfma_f32_16x16x32_bf16(vv[nf], pu.v, acc_o[mi][nf], 0, 0, 0);
      }
    }

    __syncthreads();   // drains prefetch (overlapped) + protects buffer reuse
    cur ^= 1;
  }
#undef STAGE

  // --- epilogue: O^T -> O, packed ushort4 (hd contiguous per lane) ---
#pragma unroll
  for (int mi = 0; mi < 2; ++mi) {
    const float rl = 1.0f / l_run[mi];
    const int row = b * SEQ + qr0 + mi * 16 + l15;
#pragma unroll
    for (int nf = 0; nf < 4; ++nf) {
      ushort4 pk;
      pk.x = f2bf(acc_o[mi][nf][0] * rl);
      pk.y = f2bf(acc_o[mi][nf][1] * rl);
      pk.z = f2bf(acc_o[mi][nf][2] * rl);
      pk.w = f2bf(acc_o[mi][nf][3] * rl);
      *(ushort4*)&O[(size_t)row * DMODEL + h * HD + nf * 16 + lg * 4] = pk;
    }
  }
}

// ---------- launch ----------
extern "C" void kernel_launch(void* const* d_in, const int* in_sizes, int n_in,
                              void* d_out, int out_size, void* d_ws, size_t ws_size,
                              hipStream_t stream) {
  const float* x     = (const float*)d_in[0];
  const float* Wqkv  = (const float*)d_in[1];
  const float* bqkv  = (const float*)d_in[2];
  const float* Wproj = (const float*)d_in[3];
  const float* bproj = (const float*)d_in[4];
  float* out = (float*)d_out;

  char* ws = (char*)d_ws;
  ushort* x_bf     = (ushort*)ws;                      // 16MB (reused as attn-out)
  ushort* ao       = x_bf;
  ushort* wqkv_bf  = (ushort*)(ws + (16u << 20));      // 6MB
  ushort* wproj_bf = (ushort*)(ws + (22u << 20));      // 2MB
  ushort* q        = (ushort*)(ws + (24u << 20));      // 16MB each
  ushort* k        = (ushort*)(ws + (40u << 20));
  ushort* vt       = (ushort*)(ws + (56u << 20));      // V transposed [B,H,HD,SEQ]

  cvt_kernel<<<(MTOT * DMODEL / 4) / 256, 256, 0, stream>>>(x, x_bf, MTOT * DMODEL / 4);
  cvt_kernel<<<(3 * DMODEL * DMODEL / 4) / 256, 256, 0, stream>>>(Wqkv, wqkv_bf, 3 * DMODEL * DMODEL / 4);
  cvt_kernel<<<(DMODEL * DMODEL / 4) / 256, 256, 0, stream>>>(Wproj, wproj_bf, DMODEL * DMODEL / 4);

  gemm_nt<0><<<dim3(3 * DMODEL / 128, MTOT / 128), 256, 0, stream>>>(
      x_bf, wqkv_bf, bqkv, nullptr, q, k, vt, MTOT, 3 * DMODEL, DMODEL);

  attn_kernel<<<dim3(SEQ / 128, BATCH * NH), 256, 0, stream>>>(q, k, vt, ao);

  gemm_nt<1><<<dim3(DMODEL / 128, MTOT / 128), 256, 0, stream>>>(
      ao, wproj_bf, bproj, out, nullptr, nullptr, nullptr, MTOT, DMODEL, DMODEL);
}